// Round 10
// baseline (650.745 us; speedup 1.0000x reference)
//
#include <hip/hip_runtime.h>

// QLORA: Y = X @ (W_nf4*c1*c2) + (X @ L1) @ L2
// M=8192, K=4096, N=4096, RANK=16.
// R13 changes vs R12 (single change):
//  - GEMM K-loop: 2-deep counted-vmcnt pipeline at TILE granularity.
//    BK=32 double-buffer (same 32KB LDS / swizzle / frags / epilogue).
//    Per tile: {ds_read frags -> regs; lgkmcnt(0); barrier;
//               stage(t+2) into the just-freed buffer; 8x MFMA;
//               vmcnt(4) [completes tile t+1]; barrier}.
//    Never vmcnt(0) in the main loop (the documented ~20% full-drain stall
//    of the __syncthreads family). Ledger is uniform (4 loads/wave/tile) --
//    the R4/R6 per-phase count-drift failure mode is structurally absent;
//    tail peeled (t=126 stages nothing + vmcnt(0); t=127 wait-free).
//  - Everything else byte-identical to R12 (636us session best).

#define M_ROWS 8192
#define K_DIM  4096
#define N_OUT  4096
#define XL1_BLOCKS 512          // M/16, each: 16 rows x full K + Xh store
#define WP_BLOCKS  4096         // (N/64)*(K/64)
#define NTILES 128              // K_DIM / 32

typedef float  f32x16 __attribute__((ext_vector_type(16)));
typedef float  f32x4  __attribute__((ext_vector_type(4)));
typedef __bf16 bf16x8 __attribute__((ext_vector_type(8)));
typedef unsigned short ushort8v __attribute__((ext_vector_type(8)));

__device__ float          Tg[(size_t)M_ROWS * 16];   // T = X@L1, fp32
__device__ unsigned short L1t[16 * K_DIM];           // L1^T, bf16
__device__ unsigned short L2t[N_OUT * 16];           // L2^T, bf16

__device__ __forceinline__ unsigned short f2bf(float f) {
    __bf16 h = (__bf16)f;                       // native v_cvt (RNE)
    union { __bf16 h; unsigned short u; } v; v.h = h;
    return v.u;
}

// ------------------- tiny transposes: L1 -> L1t (bf16), L2 -> L2t (bf16)
__global__ __launch_bounds__(256) void lorap_kernel(
        const float* __restrict__ L1, const float* __restrict__ L2) {
    const int idx = blockIdx.x * 256 + threadIdx.x;
    if (idx < K_DIM) {                       // L1t, thread = one k
        const float4* lp = (const float4*)&L1[(size_t)idx * 16];
        float4 r0 = lp[0], r1 = lp[1], r2 = lp[2], r3 = lp[3];
        float v[16] = {r0.x, r0.y, r0.z, r0.w, r1.x, r1.y, r1.z, r1.w,
                       r2.x, r2.y, r2.z, r2.w, r3.x, r3.y, r3.z, r3.w};
        #pragma unroll
        for (int r = 0; r < 16; ++r)
            L1t[(size_t)r * K_DIM + idx] = f2bf(v[r]);
    } else {                                 // L2t, thread = one n
        const int n = idx - K_DIM;
        ushort8v a, b;
        #pragma unroll
        for (int r = 0; r < 8; ++r) a[r] = f2bf(L2[(size_t)r * N_OUT + n]);
        #pragma unroll
        for (int r = 0; r < 8; ++r) b[r] = f2bf(L2[(size_t)(r + 8) * N_OUT + n]);
        *(ushort8v*)&L2t[(size_t)n * 16]     = a;
        *(ushort8v*)&L2t[(size_t)n * 16 + 8] = b;
    }
}

// --------------- merged prep: xl1+cvt (blocks 0..511) | wprep (512..4607)
__global__ __launch_bounds__(256) void prep_all_kernel(
        const float* __restrict__ X,    unsigned short* __restrict__ Xh,
        const float* __restrict__ Wnf4, const float* __restrict__ c1p,
        const float* __restrict__ c2,   unsigned short* __restrict__ Wt) {
    const int t = threadIdx.x;

    if (blockIdx.x < XL1_BLOCKS) {
        // ---- T = X @ L1 (16 rows, full K, 4-wave K-split) + Xh side-write.
        __shared__ float red[4][256];
        const int m0 = blockIdx.x * 16;
        const int wv = t >> 6, lane = t & 63;
        const int l15 = lane & 15, l4 = lane >> 4;
        const size_t rowoff = (size_t)(m0 + l15) * K_DIM + wv * 1024 + l4 * 8;
        const float* ap = X + rowoff;
        unsigned short* xp = Xh + rowoff;
        const __bf16* bp = (const __bf16*)L1t + (size_t)l15 * K_DIM + wv * 1024 + l4 * 8;
        f32x4 acc = {};
        #pragma unroll 8
        for (int k = 0; k < 1024; k += 32) {
            float4 p0 = *(const float4*)(ap + k);
            float4 p1 = *(const float4*)(ap + k + 4);
            bf16x8 a;
            a[0] = (__bf16)p0.x; a[1] = (__bf16)p0.y;
            a[2] = (__bf16)p0.z; a[3] = (__bf16)p0.w;
            a[4] = (__bf16)p1.x; a[5] = (__bf16)p1.y;
            a[6] = (__bf16)p1.z; a[7] = (__bf16)p1.w;
            *(bf16x8*)(xp + k) = a;                  // cvt fused: Xh store
            bf16x8 b = *(const bf16x8*)(bp + k);
            acc = __builtin_amdgcn_mfma_f32_16x16x32_bf16(a, b, acc, 0, 0, 0);
        }
        #pragma unroll
        for (int r = 0; r < 4; ++r) red[wv][(l4 * 4 + r) * 16 + l15] = acc[r];
        __syncthreads();
        if (wv == 0) {
            #pragma unroll
            for (int r = 0; r < 4; ++r) {
                int e = (l4 * 4 + r) * 16 + l15;
                Tg[(size_t)(m0 + l4 * 4 + r) * 16 + l15] =
                    red[0][e] + red[1][e] + red[2][e] + red[3][e];
            }
        }
        return;
    }

    // ---- W' = W_nf4*c1*c2, transposed store via LDS 64x64 tile (one-shot)
    {
        __shared__ unsigned short tile[64][72];   // [n][k], pad 8 = 16B align
        const int wb = blockIdx.x - XL1_BLOCKS;
        const int n0 = (wb & 63) * 64;
        const int k0 = (wb >> 6) * 64;
        const float c1 = *c1p;

        #pragma unroll
        for (int i = 0; i < 4; ++i) {
            int idx = i * 1024 + t * 4;
            int k = idx >> 6, n4 = idx & 63;
            size_t g = (size_t)(k0 + k) * N_OUT + n0 + n4;
            float4 w = *(const float4*)&Wnf4[g];
            float4 s = *(const float4*)&c2[g];
            tile[n4    ][k] = f2bf(w.x * c1 * s.x);
            tile[n4 + 1][k] = f2bf(w.y * c1 * s.y);
            tile[n4 + 2][k] = f2bf(w.z * c1 * s.z);
            tile[n4 + 3][k] = f2bf(w.w * c1 * s.w);
        }
        __syncthreads();

        #pragma unroll
        for (int i = 0; i < 2; ++i) {
            int task = i * 256 + t;
            int n = task >> 3, k8 = (task & 7) * 8;
            ushort8v o = *(const ushort8v*)&tile[n][k8];
            *(ushort8v*)&Wt[(size_t)(n0 + n) * K_DIM + k0 + k8] = o;
        }
    }
}

// ----------------------------------------------------------------- bf16 GEMM
// C[M][N] = A[M][K]*Bt[N][K]^T + T@L2t^T ; 128x128 tile, BK=32 dbuf,
// 2-deep counted-vmcnt pipeline, 4 waves, verified R5 swizzle.
// m_base: M-half offset (launched 2x, 4096 rows each).
#define FBAR() do { asm volatile("" ::: "memory"); \
    __builtin_amdgcn_s_barrier(); asm volatile("" ::: "memory"); } while (0)

#define STG(B, KS) do { \
    const int kb_ = (KS) * 32; \
    _Pragma("unroll") for (int j = 0; j < 2; ++j) { \
        int row = w * 32 + j * 16 + srow; \
        const __bf16* ga = A + (size_t)(m0 + row) * K_DIM + kb_ + scol; \
        __builtin_amdgcn_global_load_lds( \
            (const __attribute__((address_space(1))) unsigned int*)ga, \
            (__attribute__((address_space(3))) unsigned int*) \
                (&As[B][0] + (w * 32 + j * 16) * 32), 16, 0, 0); \
        const __bf16* gb = Bt + (size_t)(n0 + row) * K_DIM + kb_ + scol; \
        __builtin_amdgcn_global_load_lds( \
            (const __attribute__((address_space(1))) unsigned int*)gb, \
            (__attribute__((address_space(3))) unsigned int*) \
                (&Bs[B][0] + (w * 32 + j * 16) * 32), 16, 0, 0); \
    } \
} while (0)

#define LOAD_FRAGS(B) do { \
    _Pragma("unroll") for (int mt = 0; mt < 2; ++mt) \
      _Pragma("unroll") for (int ks = 0; ks < 2; ++ks) { \
        int row = wm + mt * 32 + l32; \
        int slot = (2 * ks + half) ^ rsw; \
        af[mt][ks] = *(const bf16x8*)(&As[B][0] + row * 32 + slot * 8); \
      } \
    _Pragma("unroll") for (int nt = 0; nt < 2; ++nt) \
      _Pragma("unroll") for (int ks = 0; ks < 2; ++ks) { \
        int row = wn + nt * 32 + l32; \
        int slot = (2 * ks + half) ^ rsw; \
        bfr[nt][ks] = *(const bf16x8*)(&Bs[B][0] + row * 32 + slot * 8); \
      } \
} while (0)

#define DO_MFMA() do { \
    _Pragma("unroll") for (int ks = 0; ks < 2; ++ks) \
      _Pragma("unroll") for (int mt = 0; mt < 2; ++mt) \
        _Pragma("unroll") for (int nt = 0; nt < 2; ++nt) \
          acc[mt][nt] = __builtin_amdgcn_mfma_f32_32x32x16_bf16( \
              af[mt][ks], bfr[nt][ks], acc[mt][nt], 0, 0, 0); \
} while (0)

__global__ __launch_bounds__(256) void gemm_bt_kernel(
        const __bf16* __restrict__ A, const __bf16* __restrict__ Bt,
        float* __restrict__ C, int m_base) {
    __shared__ __bf16 As[2][128 * 32];   // 2 x 8 KB
    __shared__ __bf16 Bs[2][128 * 32];   // 2 x 8 KB

    const int t    = threadIdx.x;
    const int w    = t >> 6;
    const int lane = t & 63;
    const int half = lane >> 5;       // 0..1
    const int l32  = lane & 31;

    const int m0   = m_base + blockIdx.y * 128;
    const int n0   = blockIdx.x * 128;

    const int wm   = (w >> 1) * 64;
    const int wn   = (w & 1) * 64;

    // staging source permutation: lane l -> row l>>2,
    // phys slot l&3 holds logical slot (l&3)^((l>>3)&3)
    const int srow = lane >> 2;
    const int scol = ((lane & 3) ^ ((lane >> 3) & 3)) * 8;
    // read-side swizzle: (row>>1)&3 with row = base32 + l32
    const int rsw = (l32 >> 1) & 3;

    f32x16 acc[2][2] = {};
    bf16x8 af[2][2], bfr[2][2];

    // prologue: tiles 0 (buf0) and 1 (buf1); vmcnt(4) completes tile 0.
    STG(0, 0);
    STG(1, 1);
    asm volatile("s_waitcnt vmcnt(4)" ::: "memory");
    FBAR();

    // main: t = 0..125. Entry invariant: buf[t&1] holds tile t complete;
    // tile t+1's 4 loads in flight. vmcnt(4) after staging t+2 completes t+1.
    for (int tt = 0; tt < NTILES - 2; ++tt) {
        const int cur = tt & 1;
        LOAD_FRAGS(cur);
        asm volatile("s_waitcnt lgkmcnt(0)" ::: "memory");
        FBAR();                               // read-release: buf[cur] free
        STG(cur, tt + 2);                     // overwrite with tile t+2
        DO_MFMA();                            // overlaps t+1 landing, t+2 flight
        asm volatile("s_waitcnt vmcnt(4)" ::: "memory");
        FBAR();                               // buf[cur^1] = tile t+1 ready
    }
    // t = 126: no stage; drain tile 127's loads.
    LOAD_FRAGS(0);
    asm volatile("s_waitcnt lgkmcnt(0)" ::: "memory");
    FBAR();
    DO_MFMA();
    asm volatile("s_waitcnt vmcnt(0)" ::: "memory");
    FBAR();
    // t = 127: wait-free.
    LOAD_FRAGS(1);
    DO_MFMA();

    // ---- LoRA epilogue (verified in R5): acc += T(128x16) @ L2t^T, K=16.
    {
        bf16x8 afl[2], bfl[2];
        #pragma unroll
        for (int mt = 0; mt < 2; ++mt) {
            const float* tp = Tg + (size_t)(m0 + wm + mt * 32 + l32) * 16 + half * 8;
            float4 p0 = *(const float4*)tp;
            float4 p1 = *(const float4*)(tp + 4);
            afl[mt][0] = (__bf16)p0.x; afl[mt][1] = (__bf16)p0.y;
            afl[mt][2] = (__bf16)p0.z; afl[mt][3] = (__bf16)p0.w;
            afl[mt][4] = (__bf16)p1.x; afl[mt][5] = (__bf16)p1.y;
            afl[mt][6] = (__bf16)p1.z; afl[mt][7] = (__bf16)p1.w;
        }
        #pragma unroll
        for (int nt = 0; nt < 2; ++nt)
            bfl[nt] = *(const bf16x8*)((const __bf16*)L2t +
                        (size_t)(n0 + wn + nt * 32 + l32) * 16 + half * 8);
        #pragma unroll
        for (int mt = 0; mt < 2; ++mt)
            #pragma unroll
            for (int nt = 0; nt < 2; ++nt)
                acc[mt][nt] = __builtin_amdgcn_mfma_f32_32x32x16_bf16(
                    afl[mt], bfl[nt], acc[mt][nt], 0, 0, 0);
    }

    // epilogue: C/D 32x32 layout col=lane&31, row=(reg&3)+8*(reg>>2)+4*half
    #pragma unroll
    for (int mt = 0; mt < 2; ++mt)
        #pragma unroll
        for (int nt = 0; nt < 2; ++nt) {
            int col = n0 + wn + nt * 32 + l32;
            #pragma unroll
            for (int reg = 0; reg < 16; ++reg) {
                int row = m0 + wm + mt * 32 + (reg & 3) + 8 * (reg >> 2) + 4 * half;
                C[(size_t)row * N_OUT + col] = acc[mt][nt][reg];
            }
        }
}

extern "C" void kernel_launch(void* const* d_in, const int* in_sizes, int n_in,
                              void* d_out, int out_size, void* d_ws, size_t ws_size,
                              hipStream_t stream) {
    const float* X    = (const float*)d_in[0];
    const float* Wnf4 = (const float*)d_in[1];
    const float* c1   = (const float*)d_in[2];   // scalar
    const float* c2   = (const float*)d_in[3];
    const float* L1   = (const float*)d_in[4];
    const float* L2   = (const float*)d_in[5];
    float* Y = (float*)d_out;

    unsigned short* Xh = (unsigned short*)d_ws;                                       // 64 MB
    unsigned short* Wt = (unsigned short*)((char*)d_ws + (size_t)M_ROWS * K_DIM * 2); // 32 MB

    lorap_kernel<<<32, 256, 0, stream>>>(L1, L2);
    prep_all_kernel<<<XL1_BLOCKS + WP_BLOCKS, 256, 0, stream>>>(
        X, Xh, Wnf4, c1, c2, Wt);

    // GEMM in 2 M-halves (1024 blocks = 4/CU each).
    gemm_bt_kernel<<<dim3(N_OUT / 128, 32), 256, 0, stream>>>(
        (const __bf16*)Xh, (const __bf16*)Wt, Y, 0);
    gemm_bt_kernel<<<dim3(N_OUT / 128, 32), 256, 0, stream>>>(
        (const __bf16*)Xh, (const __bf16*)Wt, Y, 4096);
}